// Round 1
// baseline (116.946 us; speedup 1.0000x reference)
//
#include <hip/hip_runtime.h>
#include <math.h>

#define B_    2
#define C_    64
#define N_    20000
#define K_    16
#define COUT_ 64
#define TN1   64
#define NB1   ((N_ + TN1 - 1) / TN1)   // 313
#define TN2   16
#define NB2   (N_ / TN2)               // 1250 (exact, no tail)
#define NCH   2                        // channel chunks: 32 ch = 64 B rows

typedef unsigned int   u32;
typedef unsigned short u16;

static __device__ __forceinline__ u16 f2bf(float f) {
    union { float f; u32 u; } v; v.f = f;
    u32 r = (v.u + 0x7FFFu + ((v.u >> 16) & 1u)) >> 16;  // RNE
    return (u16)r;
}
static __device__ __forceinline__ float uasf(u32 u) {
    union { u32 u; float f; } v; v.u = u; return v.f;
}

// ---------------------------------------------------------------------------
// Kernel 0: edge prep, ONCE per edge (was re-done per stage2 tile; with the
// chunk split it would have been re-done NCH times). Packs (i0,i1,s) into
// 8 B so each stage2 chunk pass reads edges coalesced, no pos gathers,
// no phase-A barrier.
// ---------------------------------------------------------------------------
__global__ __launch_bounds__(256)
void edgeprep(const int* __restrict__ ei, const float* __restrict__ pos,
              uint2* __restrict__ ebuf) {
    const int g  = blockIdx.x * 256 + threadIdx.x;     // 0 .. B*N*K-1
    const int b  = g / (N_ * K_);
    const int i0 = ei[g];                              // neighbor (y table)
    const int i1 = ei[B_ * N_ * K_ + g];               // center   (z table)
    const float* pb = pos + (size_t)b * 3 * N_;
    float dx = pb[i0]          - pb[i1];
    float dy = pb[N_ + i0]     - pb[N_ + i1];
    float dz = pb[2 * N_ + i0] - pb[2 * N_ + i1];
    float dis = sqrtf(dx * dx + dy * dy + dz * dz);
    float s = 2.0f / (1.0f + __expf(dis));             // 2*sigmoid(-dis)
    ebuf[g] = make_uint2((u32)i0 | ((u32)i1 << 16), __float_as_uint(s));
}

// ---------------------------------------------------------------------------
// Stage 1: per-node GEMM. z = (W1-W2)x + b, y = W2 x -> bf16 tables.
// NEW layout: [chunk][b][n][32ch] (64 B rows) so stage2's active working
// set per (b,chunk) phase is 2.56 MB — resident in one XCD's 4 MiB L2.
// Core compute unchanged (round-6 proven: LDS weights, named accumulators).
// ---------------------------------------------------------------------------
__global__ __launch_bounds__(256)
void stage1(const float* __restrict__ x, const float* __restrict__ W,
            const float* __restrict__ bias,
            u16* __restrict__ zbuf, u16* __restrict__ ybuf) {
    __shared__ float xt[64][68];    // [c][n_local], rows 16B-aligned
    __shared__ float wc[64][130];   // [c][2*o+{0,1}] = (w1-w2, w2)

    const int bi   = blockIdx.x;
    const int b    = bi / NB1;
    const int n0   = (bi % NB1) * TN1;
    const int t    = threadIdx.x;
    const int lane = t & 63;        // = output channel o
    const int w    = t >> 6;

    // ---- stage weights (coalesced): 64o x 64c ----
    #pragma unroll
    for (int r = 0; r < 16; ++r) {
        int flat = r * 256 + t;
        int o = flat >> 6, c = flat & 63;
        float w1 = W[o * 128 + c];
        float w2 = W[o * 128 + 64 + c];
        wc[c][2 * o]     = w1 - w2;
        wc[c][2 * o + 1] = w2;
    }
    // ---- stage x tile [c][n] via float4 (coalesced) ----
    const float* xb = x + (size_t)b * C_ * N_;
    #pragma unroll
    for (int r = 0; r < 4; ++r) {
        int flat = r * 256 + t;
        int c = flat >> 4, ng = (flat & 15) * 4;
        int n = n0 + ng;
        float4 v;
        if (n + 3 < N_) {
            v = *(const float4*)&xb[c * N_ + n];
        } else {
            v.x = (n     < N_) ? xb[c * N_ + n    ] : 0.0f;
            v.y = (n + 1 < N_) ? xb[c * N_ + n + 1] : 0.0f;
            v.z = (n + 2 < N_) ? xb[c * N_ + n + 2] : 0.0f;
            v.w = (n + 3 < N_) ? xb[c * N_ + n + 3] : 0.0f;
        }
        *(float4*)&xt[c][ng] = v;
    }
    const float bo = bias[lane];
    __syncthreads();

    // ---- wave computes 16 nodes, all accumulators NAMED float4 ----
    const int nb = w * 16;
    float4 z0 = {bo,bo,bo,bo}, z1 = z0, z2 = z0, z3 = z0;
    float4 y0 = {0,0,0,0},     y1 = y0, y2 = y0, y3 = y0;

#define FMA4(ZR, YR, XV) \
    ZR.x = fmaf(wv.x, XV.x, ZR.x);  YR.x = fmaf(wv.y, XV.x, YR.x); \
    ZR.y = fmaf(wv.x, XV.y, ZR.y);  YR.y = fmaf(wv.y, XV.y, YR.y); \
    ZR.z = fmaf(wv.x, XV.z, ZR.z);  YR.z = fmaf(wv.y, XV.z, YR.z); \
    ZR.w = fmaf(wv.x, XV.w, ZR.w);  YR.w = fmaf(wv.y, XV.w, YR.w);

    #pragma unroll 2
    for (int c = 0; c < 64; ++c) {
        float2 wv = *(const float2*)&wc[c][2 * lane];   // conflict-free
        float4 xa = *(const float4*)&xt[c][nb];         // uniform broadcasts
        float4 xv1 = *(const float4*)&xt[c][nb + 4];
        float4 xv2 = *(const float4*)&xt[c][nb + 8];
        float4 xv3 = *(const float4*)&xt[c][nb + 12];
        FMA4(z0, y0, xa)
        FMA4(z1, y1, xv1)
        FMA4(z2, y2, xv2)
        FMA4(z3, y3, xv3)
    }
#undef FMA4

    {
        // chunked store: chunk = o>>5, within-chunk channel = o&31
        const size_t chb = ((size_t)(lane >> 5) * B_ + b) * N_;
        auto st = [&](int i, float zv, float yv) {
            int n = n0 + nb + i;
            if (n < N_) {
                size_t off = (chb + n) * 32 + (lane & 31);  // 64 B coalesced
                zbuf[off] = f2bf(zv);
                ybuf[off] = f2bf(yv);
            }
        };
        st(0,  z0.x, y0.x); st(1,  z0.y, y0.y); st(2,  z0.z, y0.z); st(3,  z0.w, y0.w);
        st(4,  z1.x, y1.x); st(5,  z1.y, y1.y); st(6,  z1.z, y1.z); st(7,  z1.w, y1.w);
        st(8,  z2.x, y2.x); st(9,  z2.y, y2.y); st(10, z2.z, y2.z); st(11, z2.w, y2.w);
        st(12, z3.x, y3.x); st(13, z3.y, y3.y); st(14, z3.z, y3.z); st(15, z3.w, y3.w);
    }
}

// ---------------------------------------------------------------------------
// Stage 2: gather + relu + suppress + k-max, channel-chunked.
// Grid order [b][chunk][tile]: concurrent blocks all work one (b,chunk)
// phase -> gather working set 2.56 MB, L2-resident per XCD.
// Lane map: nl = node(16), ks = k-group(4, each owns k = 4i+ks), cq =
// 16 B channel chunk(4). Edge records read directly from ebuf (L2-hot,
// 4-lane broadcast); no phase-A, no first barrier.
// ---------------------------------------------------------------------------
__global__ __launch_bounds__(256)
void stage2(const uint2* __restrict__ ebuf,
            const u16* __restrict__ zbuf, const u16* __restrict__ ybuf,
            float* __restrict__ out) {
    __shared__ float tile[TN2][34];      // [n_local][32 ch], rows 8B-aligned

    const int bi  = blockIdx.x;          // [B][NCH][NB2]
    const int b   = bi / (NCH * NB2);
    const int rem = bi % (NCH * NB2);
    const int ch  = rem / NB2;
    const int n0  = (rem % NB2) * TN2;
    const int t   = threadIdx.x;
    const int nl  = t >> 4;              // node 0..15
    const int ks  = (t >> 2) & 3;        // k-group 0..3
    const int cq  = t & 3;               // 16 B chunk = 8 channels

    const uint2* eb = ebuf + (size_t)b * N_ * K_ + (size_t)(n0 + nl) * K_ + ks;
    const u16*   zb = zbuf + ((size_t)ch * B_ + b) * N_ * 32;
    const u16*   yb = ybuf + ((size_t)ch * B_ + b) * N_ * 32;

    float4 ma = {0,0,0,0}, mb = {0,0,0,0};   // 8 channel maxima (named)

#define COMB(ZW, YW, MLO, MHI) { \
    float zl = uasf((ZW) << 16), zh = uasf((ZW) & 0xFFFF0000u); \
    float yl = uasf((YW) << 16), yh = uasf((YW) & 0xFFFF0000u); \
    MLO = fmaxf(MLO, fmaxf(zl + yl, 0.0f) * s); \
    MHI = fmaxf(MHI, fmaxf(zh + yh, 0.0f) * s); }

    #pragma unroll
    for (int i = 0; i < 4; ++i) {
        uint2 e = eb[4 * i];             // k = 4*i + ks (4-lane broadcast)
        int   i0 = (int)(e.x & 0xFFFFu);
        int   i1 = (int)(e.x >> 16);
        float s  = uasf(e.y);
        uint4 z4 = *((const uint4*)(zb + ((size_t)i1 << 5)) + cq);  // 16 B
        uint4 y4 = *((const uint4*)(yb + ((size_t)i0 << 5)) + cq);
        COMB(z4.x, y4.x, ma.x, ma.y)
        COMB(z4.y, y4.y, ma.z, ma.w)
        COMB(z4.z, y4.z, mb.x, mb.y)
        COMB(z4.w, y4.w, mb.z, mb.w)
    }
#undef COMB

    // ---- merge the four k-groups (lane bits 2..3 = ks) ----
    ma.x = fmaxf(ma.x, __shfl_xor(ma.x, 4));
    ma.y = fmaxf(ma.y, __shfl_xor(ma.y, 4));
    ma.z = fmaxf(ma.z, __shfl_xor(ma.z, 4));
    ma.w = fmaxf(ma.w, __shfl_xor(ma.w, 4));
    mb.x = fmaxf(mb.x, __shfl_xor(mb.x, 4));
    mb.y = fmaxf(mb.y, __shfl_xor(mb.y, 4));
    mb.z = fmaxf(mb.z, __shfl_xor(mb.z, 4));
    mb.w = fmaxf(mb.w, __shfl_xor(mb.w, 4));
    ma.x = fmaxf(ma.x, __shfl_xor(ma.x, 8));
    ma.y = fmaxf(ma.y, __shfl_xor(ma.y, 8));
    ma.z = fmaxf(ma.z, __shfl_xor(ma.z, 8));
    ma.w = fmaxf(ma.w, __shfl_xor(ma.w, 8));
    mb.x = fmaxf(mb.x, __shfl_xor(mb.x, 8));
    mb.y = fmaxf(mb.y, __shfl_xor(mb.y, 8));
    mb.z = fmaxf(mb.z, __shfl_xor(mb.z, 8));
    mb.w = fmaxf(mb.w, __shfl_xor(mb.w, 8));

    if (ks == 0) {
        int cb = cq * 8;
        *(float2*)&tile[nl][cb]     = make_float2(ma.x, ma.y);
        *(float2*)&tile[nl][cb + 2] = make_float2(ma.z, ma.w);
        *(float2*)&tile[nl][cb + 4] = make_float2(mb.x, mb.y);
        *(float2*)&tile[nl][cb + 6] = make_float2(mb.z, mb.w);
    }
    __syncthreads();

    // ---- coalesced writeback: 32 o x 16 n (nontemporal: keep tables hot) ----
    #pragma unroll
    for (int r = 0; r < 2; ++r) {
        int flat = r * 256 + t;
        int o = flat >> 4, n2 = flat & 15;
        __builtin_nontemporal_store(tile[n2][o],
            &out[((size_t)b * COUT_ + ch * 32 + o) * N_ + n0 + n2]);
    }
}

// ---------------------------------------------------------------------------
extern "C" void kernel_launch(void* const* d_in, const int* in_sizes, int n_in,
                              void* d_out, int out_size, void* d_ws, size_t ws_size,
                              hipStream_t stream) {
    const float* x    = (const float*)d_in[0];   // [B, C, N, 1]
    const int*   ei   = (const int*)  d_in[1];   // [2, B, N, K]
    const float* pos  = (const float*)d_in[2];   // [B, 3, N, 1]
    const float* W    = (const float*)d_in[3];   // [COUT, 2C]
    const float* bias = (const float*)d_in[4];   // [COUT]
    float*       out  = (float*)d_out;           // [B, COUT, N, 1]

    const size_t tabElems = (size_t)NCH * B_ * N_ * 32;      // 2.56M u16
    u16*   zbuf = (u16*)d_ws;                                // 5.12 MB
    u16*   ybuf = zbuf + tabElems;                           // 5.12 MB
    uint2* ebuf = (uint2*)(ybuf + tabElems);                 // 5.12 MB, 8B-aligned

    hipLaunchKernelGGL(edgeprep, dim3((B_ * N_ * K_) / 256), dim3(256), 0, stream,
                       ei, pos, ebuf);
    hipLaunchKernelGGL(stage1, dim3(B_ * NB1), dim3(256), 0, stream,
                       x, W, bias, zbuf, ybuf);
    hipLaunchKernelGGL(stage2, dim3(B_ * NCH * NB2), dim3(256), 0, stream,
                       ebuf, zbuf, ybuf, out);
}